// Round 7
// baseline (351.305 us; speedup 1.0000x reference)
//
#include <hip/hip_runtime.h>
#include <hip/hip_bf16.h>
#include <cmath>

// Problem constants (from reference)
#define N_TOK 32768
#define KDIM  1024
#define ODIM  1024

// GEMM tile: 128x128 block, BK=64, 8 waves duty-split:
//   waves 0-3: mean GEMM (A = x bf16), waves 4-7: var GEMM (A = x^2 bf16)
// MODE 2: x and x^2 both pre-converted in ws -> all staging via global_load_lds,
//         zero conversion VALU in the k-loop. LDS 64KB -> 2 blocks/CU.
// MODE 1: x pre-converted only; var waves square frags in-register (R6 path).
// MODE 0: in-kernel f32->bf16 conversion fallback.
#define BM 128
#define BN 128
#define BK 64
#define NKT (KDIM / BK)   // 16 k-tiles
#define THREADS 512

typedef float          f32x4  __attribute__((ext_vector_type(4)));
typedef __bf16         bf16x8 __attribute__((ext_vector_type(8)));
typedef unsigned short us8    __attribute__((ext_vector_type(8)));
typedef unsigned short us2    __attribute__((ext_vector_type(2)));

// round-to-nearest-even f32 -> bf16
static __device__ __forceinline__ unsigned short f2bf(float f) {
  unsigned u = __builtin_bit_cast(unsigned, f);
  u += 0x7FFFu + ((u >> 16) & 1u);
  return (unsigned short)(u >> 16);
}
static __device__ __forceinline__ unsigned short bfc(float f) {
  return __builtin_bit_cast(unsigned short, (__bf16)f);
}
static __device__ __forceinline__ float bf2f(unsigned short u) {
  return __builtin_bit_cast(float, (unsigned)u << 16);
}

static __device__ __forceinline__ f32x4 mfma16(us8 a, us8 b, f32x4 c) {
  return __builtin_amdgcn_mfma_f32_16x16x32_bf16(
      __builtin_bit_cast(bf16x8, a), __builtin_bit_cast(bf16x8, b), c, 0, 0, 0);
}

static __device__ __forceinline__ void gl_lds16(const void* g, void* l) {
  __builtin_amdgcn_global_load_lds(
      (const __attribute__((address_space(1))) void*)g,
      (__attribute__((address_space(3))) void*)l, 16, 0, 0);
}

// elementwise square of 8 bf16 (f32 product, RNE repack) — MODE<=1 only
static __device__ __forceinline__ us8 sqr8(us8 a) {
  us8 r;
#pragma unroll
  for (int i = 0; i < 8; ++i) {
    float f = bf2f(a[i]);
    r[i] = bfc(f * f);
  }
  return r;
}

// ---------------------------------------------------------------------------
// Prep 1: weight_logits [O][I][2] -> bf16 W_mean, W_var
// ---------------------------------------------------------------------------
__global__ void wprep_kernel(const float* __restrict__ wl,
                             unsigned short* __restrict__ wm,
                             unsigned short* __restrict__ wv) {
  int i = blockIdx.x * blockDim.x + threadIdx.x;       // 2 elems each
  f32x4 v = *reinterpret_cast<const f32x4*>(wl + (size_t)i * 4);
  float pm0 = 1.f / (1.f + expf(-v.x));
  float ps0 = 1.f / (1.f + expf(-v.y));
  float pm1 = 1.f / (1.f + expf(-v.z));
  float ps1 = 1.f / (1.f + expf(-v.w));
  float m0 = pm0 * (2.f * ps0 - 1.f);
  float m1 = pm1 * (2.f * ps1 - 1.f);
  float q0 = pm0 - m0 * m0;
  float q1 = pm1 - m1 * m1;
  us2 am = {f2bf(m0), f2bf(m1)};
  us2 av = {f2bf(q0), f2bf(q1)};
  *reinterpret_cast<us2*>(wm + (size_t)i * 2) = am;
  *reinterpret_cast<us2*>(wv + (size_t)i * 2) = av;
}

// ---------------------------------------------------------------------------
// Prep 2: x f32 -> bf16 x (and optionally bf16 x^2), row-major same layout.
// ---------------------------------------------------------------------------
template <bool SQ>
__global__ void xprep_kernel(const float* __restrict__ x,
                             unsigned short* __restrict__ xbf,
                             unsigned short* __restrict__ xbf2) {
  const int t = blockIdx.x * blockDim.x + threadIdx.x;
#pragma unroll
  for (int i = 0; i < 4; ++i) {
    size_t c = (size_t)i * 1048576 + t;
    const float* s = x + c * 8;
    f32x4 v0 = *reinterpret_cast<const f32x4*>(s);
    f32x4 v1 = *reinterpret_cast<const f32x4*>(s + 4);
    us8 o = {bfc(v0.x), bfc(v0.y), bfc(v0.z), bfc(v0.w),
             bfc(v1.x), bfc(v1.y), bfc(v1.z), bfc(v1.w)};
    *reinterpret_cast<us8*>(xbf + c * 8) = o;
    if constexpr (SQ) {
      us8 o2 = {bfc(v0.x * v0.x), bfc(v0.y * v0.y), bfc(v0.z * v0.z),
                bfc(v0.w * v0.w), bfc(v1.x * v1.x), bfc(v1.y * v1.y),
                bfc(v1.z * v1.z), bfc(v1.w * v1.w)};
      *reinterpret_cast<us8*>(xbf2 + c * 8) = o2;
    }
  }
}

// ---------------------------------------------------------------------------
// Dual GEMM + fused epilogue.
// LDS (MODE 2): AsX@0 | AsX2@16K | BsM@32K | BsV@48K  (64KB)
// LDS (MODE<2): AsX@0 | BsM@16K  | BsV@32K            (48KB)
// All tiles [rows][64] bf16, XOR-swizzled: byte ^= (row&7)<<4.
// ---------------------------------------------------------------------------
template <int MODE>
__global__ __launch_bounds__(THREADS, 2) void ternary_gemm(
    const float* __restrict__ x,
    const unsigned short* __restrict__ xbf,
    const unsigned short* __restrict__ xbf2,
    const unsigned short* __restrict__ wm,
    const unsigned short* __restrict__ wv,
    const float* __restrict__ scale,
    const float* __restrict__ shift,
    const float* __restrict__ noise,
    float* __restrict__ out) {
  __shared__ alignas(16) char smem[(MODE == 2) ? 65536 : 49152];
  constexpr int BOFF = (MODE == 2) ? 32768 : 16384;

  const int tid  = threadIdx.x;
  const int lane = tid & 63;
  const int w    = tid >> 6;       // 0..7
  const bool isVar = (w >= 4);
  const int p    = w & 3;          // region id (2x2 grid of 64x64)
  const int wr   = p >> 1;
  const int wc   = p & 1;
  const int l15  = lane & 15;
  const int l4   = lane >> 4;

  // XCD-bijective swizzle (2048 blocks % 8 == 0), bn-inner per XCD
  const int bid = blockIdx.x;
  const int swz = (bid & 7) * 256 + (bid >> 3);
  const int bm  = swz >> 3;        // 0..255
  const int bn  = swz & 7;         // 0..7
  const int rowBase = bm * BM;
  const int colBase = bn * BN;

  f32x4 acc[4][4];
#pragma unroll
  for (int i = 0; i < 4; ++i)
#pragma unroll
    for (int j = 0; j < 4; ++j) acc[i][j] = (f32x4)0.f;

  for (int kt = 0; kt < NKT; ++kt) {
    const int k0 = kt * BK;

    // ---- stage B (Wm, Wv): 4 gl_lds/thread, linear dest, inv-swizzled src
#pragma unroll
    for (int c = 0; c < 2; ++c) {
      int flat = c * THREADS + tid;      // 0..1023 16B chunks
      int row  = flat >> 3;              // 0..127
      int j    = flat & 7;
      size_t go = (size_t)(colBase + row) * KDIM + k0 + ((j ^ (row & 7)) << 3);
      gl_lds16(wm + go, smem + BOFF + flat * 16);
      gl_lds16(wv + go, smem + BOFF + 16384 + flat * 16);
    }
    // ---- stage A (x bf16, and x^2 bf16 in MODE 2)
    if constexpr (MODE >= 1) {
#pragma unroll
      for (int c = 0; c < 2; ++c) {
        int flat = c * THREADS + tid;
        int row  = flat >> 3;
        int j    = flat & 7;
        size_t go = (size_t)(rowBase + row) * KDIM + k0 + ((j ^ (row & 7)) << 3);
        gl_lds16(xbf + go, smem + flat * 16);
        if constexpr (MODE == 2)
          gl_lds16(xbf2 + go, smem + 16384 + flat * 16);
      }
    } else {
      // fallback: f32 load + convert + swizzled ds_write
#pragma unroll
      for (int c = 0; c < 2; ++c) {
        int flat = c * THREADS + tid;
        int row  = flat >> 3;
        int j    = flat & 7;
        const float* s = x + (size_t)(rowBase + row) * KDIM + k0 + j * 8;
        f32x4 v0 = *reinterpret_cast<const f32x4*>(s);
        f32x4 v1 = *reinterpret_cast<const f32x4*>(s + 4);
        us8 o = {bfc(v0.x), bfc(v0.y), bfc(v0.z), bfc(v0.w),
                 bfc(v1.x), bfc(v1.y), bfc(v1.z), bfc(v1.w)};
        int off = row * 128 + ((j * 16) ^ ((row & 7) << 4));
        *reinterpret_cast<us8*>(smem + off) = o;
      }
    }
    __syncthreads();   // drains DMA (vmcnt) + any ds_writes

    // ---- compute: 2 k-steps, 4x4 frags, single GEMM per wave
    const char* Ab = smem + ((MODE == 2 && isVar) ? 16384 : 0);
    const char* Bb = smem + BOFF + (isVar ? 16384 : 0);
#pragma unroll
    for (int ks = 0; ks < 2; ++ks) {
      const int kb = ks * 64 + (l4 << 4);
      us8 bfr[4], afr[4];
#pragma unroll
      for (int b = 0; b < 4; ++b) {
        int row = wc * 64 + b * 16 + l15;
        bfr[b] = *reinterpret_cast<const us8*>(Bb + row * 128 + (kb ^ ((row & 7) << 4)));
      }
#pragma unroll
      for (int a = 0; a < 4; ++a) {
        int row = wr * 64 + a * 16 + l15;
        afr[a] = *reinterpret_cast<const us8*>(Ab + row * 128 + (kb ^ ((row & 7) << 4)));
        if (MODE != 2 && isVar) afr[a] = sqr8(afr[a]);
      }
      __builtin_amdgcn_s_setprio(1);
#pragma unroll
      for (int a = 0; a < 4; ++a)
#pragma unroll
        for (int b = 0; b < 4; ++b)
          acc[a][b] = mfma16(afr[a], bfr[b], acc[a][b]);
      __builtin_amdgcn_s_setprio(0);
    }
    __syncthreads();   // staging LDS free for next k-tile
  }

  // ---- epilogue: bf16 cross-wave exchange (32KB), XOR'd 2-way (free).
  // mean wave p ships M rows 32..63 of its region; var ships V rows 0..31.
  unsigned short* MxB = (unsigned short*)smem;            // [4][32][64]
  unsigned short* VxB = (unsigned short*)(smem + 16384);  // [4][32][64]
  if (!isVar) {
#pragma unroll
    for (int i = 2; i < 4; ++i)
#pragma unroll
      for (int b = 0; b < 4; ++b)
#pragma unroll
        for (int j = 0; j < 4; ++j) {
          int lr = (i - 2) * 16 + l4 * 4 + j;   // 0..31
          int lc = b * 16 + l15;
          MxB[(p * 32 + lr) * 64 + (lc ^ (((lr >> 2) & 3) << 4))] = bfc(acc[i][b][j]);
        }
  } else {
#pragma unroll
    for (int i = 0; i < 2; ++i)
#pragma unroll
      for (int b = 0; b < 4; ++b)
#pragma unroll
        for (int j = 0; j < 4; ++j) {
          int lr = i * 16 + l4 * 4 + j;         // 0..31
          int lc = b * 16 + l15;
          VxB[(p * 32 + lr) * 64 + (lc ^ (((lr >> 2) & 3) << 4))] = bfc(acc[i][b][j]);
        }
  }
  __syncthreads();

  if (!isVar) {
    // finish region rows 0..31: M in regs, V from VxB
#pragma unroll
    for (int i = 0; i < 2; ++i)
#pragma unroll
      for (int b = 0; b < 4; ++b) {
        int col = colBase + wc * 64 + b * 16 + l15;
        float sc = scale[col], sh = shift[col];
#pragma unroll
        for (int j = 0; j < 4; ++j) {
          int lr = i * 16 + l4 * 4 + j;
          int lc = b * 16 + l15;
          float vv = bf2f(VxB[(p * 32 + lr) * 64 + (lc ^ (((lr >> 2) & 3) << 4))]);
          size_t idx = (size_t)(rowBase + wr * 64 + lr) * ODIM + col;
          out[idx] = fmaf(acc[i][b][j] + sqrtf(fmaxf(vv, 0.f)) * noise[idx], sc, sh);
        }
      }
  } else {
    // finish region rows 32..63: V in regs, M from MxB
#pragma unroll
    for (int i = 2; i < 4; ++i)
#pragma unroll
      for (int b = 0; b < 4; ++b) {
        int col = colBase + wc * 64 + b * 16 + l15;
        float sc = scale[col], sh = shift[col];
#pragma unroll
        for (int j = 0; j < 4; ++j) {
          int lr = (i - 2) * 16 + l4 * 4 + j;
          int lc = b * 16 + l15;
          float mm = bf2f(MxB[(p * 32 + lr) * 64 + (lc ^ (((lr >> 2) & 3) << 4))]);
          size_t idx = (size_t)(rowBase + wr * 64 + 32 + lr) * ODIM + col;
          out[idx] = fmaf(mm + sqrtf(fmaxf(acc[i][b][j], 0.f)) * noise[idx], sc, sh);
        }
      }
  }
}

// ---------------------------------------------------------------------------
extern "C" void kernel_launch(void* const* d_in, const int* in_sizes, int n_in,
                              void* d_out, int out_size, void* d_ws, size_t ws_size,
                              hipStream_t stream) {
  const float* x     = (const float*)d_in[0];   // [32768,1024]
  const float* wl    = (const float*)d_in[1];   // [1024,1024,2]
  const float* scale = (const float*)d_in[2];   // [1024]
  const float* shift = (const float*)d_in[3];   // [1024]
  const float* noise = (const float*)d_in[4];   // [32768,1024]
  float* out = (float*)d_out;

  unsigned short* wm   = (unsigned short*)d_ws;           // 2 MB
  unsigned short* wv   = wm + (size_t)ODIM * KDIM;        // 2 MB
  unsigned short* xbf  = wv + (size_t)ODIM * KDIM;        // 64 MB
  unsigned short* xbf2 = xbf + (size_t)N_TOK * KDIM;      // 64 MB

  const size_t needW  = 2ull * ODIM * KDIM * 2;
  const size_t needX  = (size_t)N_TOK * KDIM * 2;
  const int mode = (ws_size >= needW + 2 * needX) ? 2
                 : (ws_size >= needW + needX)     ? 1 : 0;

  wprep_kernel<<<(ODIM * KDIM / 2) / 256, 256, 0, stream>>>(wl, wm, wv);
  if (mode == 2)
    xprep_kernel<true><<<4096, 256, 0, stream>>>(x, xbf, xbf2);
  else if (mode == 1)
    xprep_kernel<false><<<4096, 256, 0, stream>>>(x, xbf, xbf2);

  // grid = (32768/128) * (1024/128) = 2048 blocks of 512 threads
  if (mode == 2)
    ternary_gemm<2><<<2048, THREADS, 0, stream>>>(
        x, xbf, xbf2, wm, wv, scale, shift, noise, out);
  else if (mode == 1)
    ternary_gemm<1><<<2048, THREADS, 0, stream>>>(
        x, xbf, xbf2, wm, wv, scale, shift, noise, out);
  else
    ternary_gemm<0><<<2048, THREADS, 0, stream>>>(
        x, xbf, xbf2, wm, wv, scale, shift, noise, out);
}

// Round 8
// 240.308 us; speedup vs baseline: 1.4619x; 1.4619x over previous
//
#include <hip/hip_runtime.h>
#include <hip/hip_bf16.h>
#include <cmath>

// Problem constants (from reference)
#define N_TOK 32768
#define KDIM  1024
#define ODIM  1024

// GEMM tile: 128x128 block, BK=32, 8 waves duty-split:
//   waves 0-3: mean GEMM (A = x bf16), waves 4-7: var GEMM (sqr8 in-register)
// LDS: double-buffered {AsX 8K | BsM 8K | BsV 8K} = 2 x 24KB = 48KB.
// One __syncthreads per k-tile; DMA for kt+1 issued before compute(kt).
// REGISTER BUDGET LAW (R7 lesson): waves/CU = 2048/(VGPR+AGPR). acc = 64 AGPR,
// so VGPR must stay <= 64 for 16 waves/CU. __launch_bounds__(512,4) enforces.
#define BM 128
#define BN 128
#define BK 32
#define NKT (KDIM / BK)   // 32 k-tiles
#define THREADS 512
#define BUFSZ 24576       // 3 x 8KB tiles

typedef float          f32x4  __attribute__((ext_vector_type(4)));
typedef __bf16         bf16x8 __attribute__((ext_vector_type(8)));
typedef unsigned short us8    __attribute__((ext_vector_type(8)));
typedef unsigned short us2    __attribute__((ext_vector_type(2)));

// round-to-nearest-even f32 -> bf16
static __device__ __forceinline__ unsigned short f2bf(float f) {
  unsigned u = __builtin_bit_cast(unsigned, f);
  u += 0x7FFFu + ((u >> 16) & 1u);
  return (unsigned short)(u >> 16);
}
static __device__ __forceinline__ unsigned short bfc(float f) {
  return __builtin_bit_cast(unsigned short, (__bf16)f);
}
static __device__ __forceinline__ float bf2f(unsigned short u) {
  return __builtin_bit_cast(float, (unsigned)u << 16);
}

static __device__ __forceinline__ f32x4 mfma16(us8 a, us8 b, f32x4 c) {
  return __builtin_amdgcn_mfma_f32_16x16x32_bf16(
      __builtin_bit_cast(bf16x8, a), __builtin_bit_cast(bf16x8, b), c, 0, 0, 0);
}

static __device__ __forceinline__ void gl_lds16(const void* g, void* l) {
  __builtin_amdgcn_global_load_lds(
      (const __attribute__((address_space(1))) void*)g,
      (__attribute__((address_space(3))) void*)l, 16, 0, 0);
}

// elementwise square of 8 bf16 (f32 product, RNE repack) — var waves
static __device__ __forceinline__ us8 sqr8(us8 a) {
  us8 r;
#pragma unroll
  for (int i = 0; i < 8; ++i) {
    float f = bf2f(a[i]);
    r[i] = bfc(f * f);
  }
  return r;
}

// ---------------------------------------------------------------------------
// Prep 1: weight_logits [O][I][2] -> bf16 W_mean, W_var
// ---------------------------------------------------------------------------
__global__ void wprep_kernel(const float* __restrict__ wl,
                             unsigned short* __restrict__ wm,
                             unsigned short* __restrict__ wv) {
  int i = blockIdx.x * blockDim.x + threadIdx.x;       // 2 elems each
  f32x4 v = *reinterpret_cast<const f32x4*>(wl + (size_t)i * 4);
  float pm0 = 1.f / (1.f + expf(-v.x));
  float ps0 = 1.f / (1.f + expf(-v.y));
  float pm1 = 1.f / (1.f + expf(-v.z));
  float ps1 = 1.f / (1.f + expf(-v.w));
  float m0 = pm0 * (2.f * ps0 - 1.f);
  float m1 = pm1 * (2.f * ps1 - 1.f);
  float q0 = pm0 - m0 * m0;
  float q1 = pm1 - m1 * m1;
  us2 am = {f2bf(m0), f2bf(m1)};
  us2 av = {f2bf(q0), f2bf(q1)};
  *reinterpret_cast<us2*>(wm + (size_t)i * 2) = am;
  *reinterpret_cast<us2*>(wv + (size_t)i * 2) = av;
}

// ---------------------------------------------------------------------------
// Prep 2: x f32 -> bf16 x, row-major same layout.
// ---------------------------------------------------------------------------
__global__ void xprep_kernel(const float* __restrict__ x,
                             unsigned short* __restrict__ xbf) {
  const int t = blockIdx.x * blockDim.x + threadIdx.x;
#pragma unroll
  for (int i = 0; i < 4; ++i) {
    size_t c = (size_t)i * 1048576 + t;
    const float* s = x + c * 8;
    f32x4 v0 = *reinterpret_cast<const f32x4*>(s);
    f32x4 v1 = *reinterpret_cast<const f32x4*>(s + 4);
    us8 o = {bfc(v0.x), bfc(v0.y), bfc(v0.z), bfc(v0.w),
             bfc(v1.x), bfc(v1.y), bfc(v1.z), bfc(v1.w)};
    *reinterpret_cast<us8*>(xbf + c * 8) = o;
  }
}

// ---------------------------------------------------------------------------
// Dual GEMM + fused epilogue.
// Per-buffer LDS: AsX[128][32]@0 | BsM@8K | BsV@16K, rows 64B,
// XOR-swizzled: byte_in_row ^= (row&3)<<4.
// PRE=1: x pre-converted (DMA); PRE=0: in-kernel convert fallback.
// ---------------------------------------------------------------------------
template <int PRE>
__global__ __launch_bounds__(THREADS, 4) void ternary_gemm(
    const float* __restrict__ x,
    const unsigned short* __restrict__ xbf,
    const unsigned short* __restrict__ wm,
    const unsigned short* __restrict__ wv,
    const float* __restrict__ scale,
    const float* __restrict__ shift,
    const float* __restrict__ noise,
    float* __restrict__ out) {
  __shared__ alignas(16) char smem[2 * BUFSZ];

  const int tid  = threadIdx.x;
  const int lane = tid & 63;
  const int w    = tid >> 6;       // 0..7
  const bool isVar = (w >= 4);
  const int p    = w & 3;          // region id (2x2 grid of 64x64)
  const int wr   = p >> 1;
  const int wc   = p & 1;
  const int l15  = lane & 15;
  const int l4   = lane >> 4;

  // XCD-bijective swizzle (2048 blocks % 8 == 0), bn-inner per XCD
  const int bid = blockIdx.x;
  const int swz = (bid & 7) * 256 + (bid >> 3);
  const int bm  = swz >> 3;        // 0..255
  const int bn  = swz & 7;         // 0..7
  const int rowBase = bm * BM;
  const int colBase = bn * BN;

  f32x4 acc[4][4];
#pragma unroll
  for (int i = 0; i < 4; ++i)
#pragma unroll
    for (int j = 0; j < 4; ++j) acc[i][j] = (f32x4)0.f;

  // per-thread staging geometry: 512 threads = 128 rows x 4 16B-chunks
  const int srow = tid >> 2;       // 0..127
  const int sj   = tid & 3;        // chunk in row
  const int ke   = (sj ^ (srow & 3)) << 3;   // inverse-swizzled elem offset
  const size_t gB = (size_t)(colBase + srow) * KDIM + ke;  // + k0
  const size_t gA = (size_t)(rowBase + srow) * KDIM + ke;

  // stage one k-tile into buffer buf (3 gl_lds/thread, PRE=1)
  auto stage = [&](int kt, char* buf) {
    const int k0 = kt * BK;
    gl_lds16(wm + gB + k0, buf + 8192 + tid * 16);
    gl_lds16(wv + gB + k0, buf + 16384 + tid * 16);
    if constexpr (PRE) {
      gl_lds16(xbf + gA + k0, buf + tid * 16);
    } else {
      const float* s = x + gA + k0;
      f32x4 v0 = *reinterpret_cast<const f32x4*>(s);
      f32x4 v1 = *reinterpret_cast<const f32x4*>(s + 4);
      us8 o = {bfc(v0.x), bfc(v0.y), bfc(v0.z), bfc(v0.w),
               bfc(v1.x), bfc(v1.y), bfc(v1.z), bfc(v1.w)};
      // direct swizzled ds_write (dest = row*64 + swizzled chunk)
      int off = srow * 64 + ((sj * 16) ^ ((srow & 3) << 4));
      *reinterpret_cast<us8*>(buf + off) = o;
    }
  };

  // ---- prologue
  stage(0, smem);
  __syncthreads();

  // ---- main loop: one barrier per k-tile, dbuf hides DMA latency
  for (int kt = 0; kt < NKT; ++kt) {
    const char* cur = smem + (size_t)(kt & 1) * BUFSZ;
    if (kt + 1 < NKT)
      stage(kt + 1, smem + (size_t)((kt + 1) & 1) * BUFSZ);

    const char* Bb = cur + 8192 + (isVar ? 8192 : 0);
    const int kb = l4 << 4;        // this lane's 16B chunk within the 64B row
    us8 bfr[4], afr[4];
#pragma unroll
    for (int b = 0; b < 4; ++b) {
      int row = wc * 64 + b * 16 + l15;
      bfr[b] = *reinterpret_cast<const us8*>(Bb + row * 64 + (kb ^ ((row & 3) << 4)));
    }
#pragma unroll
    for (int a = 0; a < 4; ++a) {
      int row = wr * 64 + a * 16 + l15;
      afr[a] = *reinterpret_cast<const us8*>(cur + row * 64 + (kb ^ ((row & 3) << 4)));
      if (isVar) afr[a] = sqr8(afr[a]);
    }
    __builtin_amdgcn_s_setprio(1);
#pragma unroll
    for (int a = 0; a < 4; ++a)
#pragma unroll
      for (int b = 0; b < 4; ++b)
        acc[a][b] = mfma16(afr[a], bfr[b], acc[a][b]);
    __builtin_amdgcn_s_setprio(0);

    __syncthreads();   // drains next-tile DMA (had full compute phase to land)
  }

  // ---- epilogue: bf16 cross-wave exchange (32KB), XOR'd 2-way (free).
  // mean wave p ships M rows 32..63 of its region; var ships V rows 0..31.
  unsigned short* MxB = (unsigned short*)smem;            // [4][32][64]
  unsigned short* VxB = (unsigned short*)(smem + 16384);  // [4][32][64]
  if (!isVar) {
#pragma unroll
    for (int i = 2; i < 4; ++i)
#pragma unroll
      for (int b = 0; b < 4; ++b)
#pragma unroll
        for (int j = 0; j < 4; ++j) {
          int lr = (i - 2) * 16 + l4 * 4 + j;   // 0..31
          int lc = b * 16 + l15;
          MxB[(p * 32 + lr) * 64 + (lc ^ (((lr >> 2) & 3) << 4))] = bfc(acc[i][b][j]);
        }
  } else {
#pragma unroll
    for (int i = 0; i < 2; ++i)
#pragma unroll
      for (int b = 0; b < 4; ++b)
#pragma unroll
        for (int j = 0; j < 4; ++j) {
          int lr = i * 16 + l4 * 4 + j;         // 0..31
          int lc = b * 16 + l15;
          VxB[(p * 32 + lr) * 64 + (lc ^ (((lr >> 2) & 3) << 4))] = bfc(acc[i][b][j]);
        }
  }
  __syncthreads();

  if (!isVar) {
    // finish region rows 0..31: M in regs, V from VxB
#pragma unroll
    for (int i = 0; i < 2; ++i)
#pragma unroll
      for (int b = 0; b < 4; ++b) {
        int col = colBase + wc * 64 + b * 16 + l15;
        float sc = scale[col], sh = shift[col];
#pragma unroll
        for (int j = 0; j < 4; ++j) {
          int lr = i * 16 + l4 * 4 + j;
          int lc = b * 16 + l15;
          float vv = bf2f(VxB[(p * 32 + lr) * 64 + (lc ^ (((lr >> 2) & 3) << 4))]);
          size_t idx = (size_t)(rowBase + wr * 64 + lr) * ODIM + col;
          out[idx] = fmaf(acc[i][b][j] + sqrtf(fmaxf(vv, 0.f)) * noise[idx], sc, sh);
        }
      }
  } else {
    // finish region rows 32..63: V in regs, M from MxB
#pragma unroll
    for (int i = 2; i < 4; ++i)
#pragma unroll
      for (int b = 0; b < 4; ++b) {
        int col = colBase + wc * 64 + b * 16 + l15;
        float sc = scale[col], sh = shift[col];
#pragma unroll
        for (int j = 0; j < 4; ++j) {
          int lr = (i - 2) * 16 + l4 * 4 + j;
          int lc = b * 16 + l15;
          float mm = bf2f(MxB[(p * 32 + lr) * 64 + (lc ^ (((lr >> 2) & 3) << 4))]);
          size_t idx = (size_t)(rowBase + wr * 64 + 32 + lr) * ODIM + col;
          out[idx] = fmaf(mm + sqrtf(fmaxf(acc[i][b][j], 0.f)) * noise[idx], sc, sh);
        }
      }
  }
}

// ---------------------------------------------------------------------------
extern "C" void kernel_launch(void* const* d_in, const int* in_sizes, int n_in,
                              void* d_out, int out_size, void* d_ws, size_t ws_size,
                              hipStream_t stream) {
  const float* x     = (const float*)d_in[0];   // [32768,1024]
  const float* wl    = (const float*)d_in[1];   // [1024,1024,2]
  const float* scale = (const float*)d_in[2];   // [1024]
  const float* shift = (const float*)d_in[3];   // [1024]
  const float* noise = (const float*)d_in[4];   // [32768,1024]
  float* out = (float*)d_out;

  unsigned short* wm  = (unsigned short*)d_ws;           // 2 MB
  unsigned short* wv  = wm + (size_t)ODIM * KDIM;        // 2 MB
  unsigned short* xbf = wv + (size_t)ODIM * KDIM;        // 64 MB

  const size_t need = 2ull * ODIM * KDIM * 2 + (size_t)N_TOK * KDIM * 2;
  const bool pre = (ws_size >= need);

  wprep_kernel<<<(ODIM * KDIM / 2) / 256, 256, 0, stream>>>(wl, wm, wv);
  if (pre)
    xprep_kernel<<<4096, 256, 0, stream>>>(x, xbf);

  // grid = (32768/128) * (1024/128) = 2048 blocks of 512 threads
  if (pre)
    ternary_gemm<1><<<2048, THREADS, 0, stream>>>(
        x, xbf, wm, wv, scale, shift, noise, out);
  else
    ternary_gemm<0><<<2048, THREADS, 0, stream>>>(
        x, xbf, wm, wv, scale, shift, noise, out);
}

// Round 9
// 235.893 us; speedup vs baseline: 1.4893x; 1.0187x over previous
//
#include <hip/hip_runtime.h>
#include <hip/hip_bf16.h>
#include <cmath>

// Problem constants (from reference)
#define N_TOK 32768
#define KDIM  1024
#define ODIM  1024

// GEMM tile: 128x128 block, BK=32, 8 waves duty-split:
//   waves 0-3: mean GEMM (A = x bf16), waves 4-7: var GEMM (sqr8 in-register)
// LDS: double-buffered {AsX 8K | BsM 8K | BsV 8K} = 2 x 24KB = 48KB.
// One __syncthreads per k-tile; DMA for kt+1 issued before compute(kt).
// REGISTER LAW (R7): waves/CU = 2048/(VGPR+AGPR); acc=64 AGPR -> VGPR <= 64.
// PAIRED-ROW LDS LAYOUT (R8 lesson): BK=32's 64B rows only have 4 slots ->
// inherent 4-way read conflict. Store [128][32] tiles as 64 LDS rows of 128B:
//   matrix row r -> LDS row r>>1, half r&1; slot = ((r&1)<<2 | kchunk)
//   swizzled: slot ^= (lr&7). 8 consecutive rows hit 8 distinct slots (free).
#define BM 128
#define BN 128
#define BK 32
#define NKT (KDIM / BK)   // 32 k-tiles
#define THREADS 512
#define BUFSZ 24576       // 3 x 8KB tiles

typedef float          f32x4  __attribute__((ext_vector_type(4)));
typedef __bf16         bf16x8 __attribute__((ext_vector_type(8)));
typedef unsigned short us8    __attribute__((ext_vector_type(8)));
typedef unsigned short us2    __attribute__((ext_vector_type(2)));

// round-to-nearest-even f32 -> bf16
static __device__ __forceinline__ unsigned short f2bf(float f) {
  unsigned u = __builtin_bit_cast(unsigned, f);
  u += 0x7FFFu + ((u >> 16) & 1u);
  return (unsigned short)(u >> 16);
}
static __device__ __forceinline__ unsigned short bfc(float f) {
  return __builtin_bit_cast(unsigned short, (__bf16)f);
}
static __device__ __forceinline__ float bf2f(unsigned short u) {
  return __builtin_bit_cast(float, (unsigned)u << 16);
}

static __device__ __forceinline__ f32x4 mfma16(us8 a, us8 b, f32x4 c) {
  return __builtin_amdgcn_mfma_f32_16x16x32_bf16(
      __builtin_bit_cast(bf16x8, a), __builtin_bit_cast(bf16x8, b), c, 0, 0, 0);
}

static __device__ __forceinline__ void gl_lds16(const void* g, void* l) {
  __builtin_amdgcn_global_load_lds(
      (const __attribute__((address_space(1))) void*)g,
      (__attribute__((address_space(3))) void*)l, 16, 0, 0);
}

// elementwise square of 8 bf16 (f32 product, RNE repack) — var waves
static __device__ __forceinline__ us8 sqr8(us8 a) {
  us8 r;
#pragma unroll
  for (int i = 0; i < 8; ++i) {
    float f = bf2f(a[i]);
    r[i] = bfc(f * f);
  }
  return r;
}

// ---------------------------------------------------------------------------
// Prep 1: weight_logits [O][I][2] -> bf16 W_mean, W_var
// ---------------------------------------------------------------------------
__global__ void wprep_kernel(const float* __restrict__ wl,
                             unsigned short* __restrict__ wm,
                             unsigned short* __restrict__ wv) {
  int i = blockIdx.x * blockDim.x + threadIdx.x;       // 2 elems each
  f32x4 v = *reinterpret_cast<const f32x4*>(wl + (size_t)i * 4);
  float pm0 = 1.f / (1.f + expf(-v.x));
  float ps0 = 1.f / (1.f + expf(-v.y));
  float pm1 = 1.f / (1.f + expf(-v.z));
  float ps1 = 1.f / (1.f + expf(-v.w));
  float m0 = pm0 * (2.f * ps0 - 1.f);
  float m1 = pm1 * (2.f * ps1 - 1.f);
  float q0 = pm0 - m0 * m0;
  float q1 = pm1 - m1 * m1;
  us2 am = {f2bf(m0), f2bf(m1)};
  us2 av = {f2bf(q0), f2bf(q1)};
  *reinterpret_cast<us2*>(wm + (size_t)i * 2) = am;
  *reinterpret_cast<us2*>(wv + (size_t)i * 2) = av;
}

// ---------------------------------------------------------------------------
// Prep 2: x f32 -> bf16 x, row-major same layout.
// ---------------------------------------------------------------------------
__global__ void xprep_kernel(const float* __restrict__ x,
                             unsigned short* __restrict__ xbf) {
  const int t = blockIdx.x * blockDim.x + threadIdx.x;
#pragma unroll
  for (int i = 0; i < 4; ++i) {
    size_t c = (size_t)i * 1048576 + t;
    const float* s = x + c * 8;
    f32x4 v0 = *reinterpret_cast<const f32x4*>(s);
    f32x4 v1 = *reinterpret_cast<const f32x4*>(s + 4);
    us8 o = {bfc(v0.x), bfc(v0.y), bfc(v0.z), bfc(v0.w),
             bfc(v1.x), bfc(v1.y), bfc(v1.z), bfc(v1.w)};
    *reinterpret_cast<us8*>(xbf + c * 8) = o;
  }
}

// ---------------------------------------------------------------------------
// Dual GEMM + fused epilogue.
// Per-buffer LDS: AsX@0 | BsM@8K | BsV@16K, each a [128][32] bf16 tile in
// paired-row layout (64 LDS rows x 128B, 8-slot XOR swizzle — see header).
// PRE=1: x pre-converted (DMA); PRE=0: in-kernel convert fallback.
// ---------------------------------------------------------------------------
template <int PRE>
__global__ __launch_bounds__(THREADS, 4) void ternary_gemm(
    const float* __restrict__ x,
    const unsigned short* __restrict__ xbf,
    const unsigned short* __restrict__ wm,
    const unsigned short* __restrict__ wv,
    const float* __restrict__ scale,
    const float* __restrict__ shift,
    const float* __restrict__ noise,
    float* __restrict__ out) {
  __shared__ alignas(16) char smem[2 * BUFSZ];

  const int tid  = threadIdx.x;
  const int lane = tid & 63;
  const int w    = tid >> 6;       // 0..7
  const bool isVar = (w >= 4);
  const int p    = w & 3;          // region id (2x2 grid of 64x64)
  const int wr   = p >> 1;
  const int wc   = p & 1;
  const int l15  = lane & 15;
  const int l4   = lane >> 4;

  // XCD-bijective swizzle (2048 blocks % 8 == 0), bn-inner per XCD
  const int bid = blockIdx.x;
  const int swz = (bid & 7) * 256 + (bid >> 3);
  const int bm  = swz >> 3;        // 0..255
  const int bn  = swz & 7;         // 0..7
  const int rowBase = bm * BM;
  const int colBase = bn * BN;

  f32x4 acc[4][4];
#pragma unroll
  for (int i = 0; i < 4; ++i)
#pragma unroll
    for (int j = 0; j < 4; ++j) acc[i][j] = (f32x4)0.f;

  // ---- staging geometry (paired-row layout, inverse-swizzled source) ------
  // thread owns physical 16B chunk tid: LDS row lr=tid>>3, physical slot
  // sslot=tid&7. Logical slot = sslot ^ (lr&7) -> matrix row & k-chunk.
  const int lr    = tid >> 3;              // 0..63
  const int sslot = tid & 7;
  const int lslot = sslot ^ (lr & 7);
  const int r_    = lr * 2 + (lslot >> 2); // matrix row 0..127
  const int ke    = (lslot & 3) * 8;       // element offset in k
  const size_t gB = (size_t)(colBase + r_) * KDIM + ke;  // + k0
  const size_t gA = (size_t)(rowBase + r_) * KDIM + ke;

  auto stage = [&](int kt, char* buf) {
    const int k0 = kt * BK;
    gl_lds16(wm + gB + k0, buf + 8192 + tid * 16);
    gl_lds16(wv + gB + k0, buf + 16384 + tid * 16);
    if constexpr (PRE) {
      gl_lds16(xbf + gA + k0, buf + tid * 16);
    } else {
      const float* s = x + gA + k0;
      f32x4 v0 = *reinterpret_cast<const f32x4*>(s);
      f32x4 v1 = *reinterpret_cast<const f32x4*>(s + 4);
      us8 o = {bfc(v0.x), bfc(v0.y), bfc(v0.z), bfc(v0.w),
               bfc(v1.x), bfc(v1.y), bfc(v1.z), bfc(v1.w)};
      *reinterpret_cast<us8*>(buf + tid * 16) = o;   // linear physical chunk
    }
  };

  // read-side byte offset for matrix row `row`, k-chunk l4 (16B)
  auto lbyte = [&](int row) {
    int lrr  = row >> 1;
    int slot = (((row & 1) << 2) | l4) ^ (lrr & 7);
    return lrr * 128 + slot * 16;
  };

  // ---- prologue
  stage(0, smem);
  __syncthreads();

  // ---- main loop: one barrier per k-tile, dbuf hides DMA latency
  for (int kt = 0; kt < NKT; ++kt) {
    const char* cur = smem + (size_t)(kt & 1) * BUFSZ;
    if (kt + 1 < NKT)
      stage(kt + 1, smem + (size_t)((kt + 1) & 1) * BUFSZ);

    const char* Bb = cur + 8192 + (isVar ? 8192 : 0);
    us8 bfr[4], afr[4];
#pragma unroll
    for (int b = 0; b < 4; ++b)
      bfr[b] = *reinterpret_cast<const us8*>(Bb + lbyte(wc * 64 + b * 16 + l15));
#pragma unroll
    for (int a = 0; a < 4; ++a) {
      afr[a] = *reinterpret_cast<const us8*>(cur + lbyte(wr * 64 + a * 16 + l15));
      if (isVar) afr[a] = sqr8(afr[a]);
    }
    __builtin_amdgcn_s_setprio(1);
#pragma unroll
    for (int a = 0; a < 4; ++a)
#pragma unroll
      for (int b = 0; b < 4; ++b)
        acc[a][b] = mfma16(afr[a], bfr[b], acc[a][b]);
    __builtin_amdgcn_s_setprio(0);

    __syncthreads();   // drains next-tile DMA (had full compute phase to land)
  }

  // ---- epilogue: bf16 cross-wave exchange (32KB), XOR'd 2-way (free).
  // mean wave p ships M rows 32..63 of its region; var ships V rows 0..31.
  unsigned short* MxB = (unsigned short*)smem;            // [4][32][64]
  unsigned short* VxB = (unsigned short*)(smem + 16384);  // [4][32][64]
  if (!isVar) {
#pragma unroll
    for (int i = 2; i < 4; ++i)
#pragma unroll
      for (int b = 0; b < 4; ++b)
#pragma unroll
        for (int j = 0; j < 4; ++j) {
          int lrx = (i - 2) * 16 + l4 * 4 + j;   // 0..31
          int lc = b * 16 + l15;
          MxB[(p * 32 + lrx) * 64 + (lc ^ (((lrx >> 2) & 3) << 4))] = bfc(acc[i][b][j]);
        }
  } else {
#pragma unroll
    for (int i = 0; i < 2; ++i)
#pragma unroll
      for (int b = 0; b < 4; ++b)
#pragma unroll
        for (int j = 0; j < 4; ++j) {
          int lrx = i * 16 + l4 * 4 + j;         // 0..31
          int lc = b * 16 + l15;
          VxB[(p * 32 + lrx) * 64 + (lc ^ (((lrx >> 2) & 3) << 4))] = bfc(acc[i][b][j]);
        }
  }
  __syncthreads();

  if (!isVar) {
    // finish region rows 0..31: M in regs, V from VxB
#pragma unroll
    for (int i = 0; i < 2; ++i)
#pragma unroll
      for (int b = 0; b < 4; ++b) {
        int col = colBase + wc * 64 + b * 16 + l15;
        float sc = scale[col], sh = shift[col];
#pragma unroll
        for (int j = 0; j < 4; ++j) {
          int lrx = i * 16 + l4 * 4 + j;
          int lc = b * 16 + l15;
          float vv = bf2f(VxB[(p * 32 + lrx) * 64 + (lc ^ (((lrx >> 2) & 3) << 4))]);
          size_t idx = (size_t)(rowBase + wr * 64 + lrx) * ODIM + col;
          out[idx] = fmaf(acc[i][b][j] + sqrtf(fmaxf(vv, 0.f)) * noise[idx], sc, sh);
        }
      }
  } else {
    // finish region rows 32..63: V in regs, M from MxB
#pragma unroll
    for (int i = 2; i < 4; ++i)
#pragma unroll
      for (int b = 0; b < 4; ++b) {
        int col = colBase + wc * 64 + b * 16 + l15;
        float sc = scale[col], sh = shift[col];
#pragma unroll
        for (int j = 0; j < 4; ++j) {
          int lrx = (i - 2) * 16 + l4 * 4 + j;
          int lc = b * 16 + l15;
          float mm = bf2f(MxB[(p * 32 + lrx) * 64 + (lc ^ (((lrx >> 2) & 3) << 4))]);
          size_t idx = (size_t)(rowBase + wr * 64 + 32 + lrx) * ODIM + col;
          out[idx] = fmaf(mm + sqrtf(fmaxf(acc[i][b][j], 0.f)) * noise[idx], sc, sh);
        }
      }
  }
}

// ---------------------------------------------------------------------------
extern "C" void kernel_launch(void* const* d_in, const int* in_sizes, int n_in,
                              void* d_out, int out_size, void* d_ws, size_t ws_size,
                              hipStream_t stream) {
  const float* x     = (const float*)d_in[0];   // [32768,1024]
  const float* wl    = (const float*)d_in[1];   // [1024,1024,2]
  const float* scale = (const float*)d_in[2];   // [1024]
  const float* shift = (const float*)d_in[3];   // [1024]
  const float* noise = (const float*)d_in[4];   // [32768,1024]
  float* out = (float*)d_out;

  unsigned short* wm  = (unsigned short*)d_ws;           // 2 MB
  unsigned short* wv  = wm + (size_t)ODIM * KDIM;        // 2 MB
  unsigned short* xbf = wv + (size_t)ODIM * KDIM;        // 64 MB

  const size_t need = 2ull * ODIM * KDIM * 2 + (size_t)N_TOK * KDIM * 2;
  const bool pre = (ws_size >= need);

  wprep_kernel<<<(ODIM * KDIM / 2) / 256, 256, 0, stream>>>(wl, wm, wv);
  if (pre)
    xprep_kernel<<<4096, 256, 0, stream>>>(x, xbf);

  // grid = (32768/128) * (1024/128) = 2048 blocks of 512 threads
  if (pre)
    ternary_gemm<1><<<2048, THREADS, 0, stream>>>(
        x, xbf, wm, wv, scale, shift, noise, out);
  else
    ternary_gemm<0><<<2048, THREADS, 0, stream>>>(
        x, xbf, wm, wv, scale, shift, noise, out);
}